// Round 2
// 693.100 us; speedup vs baseline: 1.0017x; 1.0017x over previous
//
#include <hip/hip_runtime.h>
#include <math.h>

#define BB 64
#define E_PER 4096
#define DD 256
#define KK 50
#define EE (BB * E_PER)

typedef float f4 __attribute__((ext_vector_type(4)));

// ---------------------------------------------------------------------------
// Kernel 1: per-edge score + fused visited passthrough copy.
// One 64-lane wave per edge; lane i owns dims [4i, 4i+4) as 16B -> 1 KB
// coalesced per stream per wave.
// score = -( |w0|*rel_loss + |w1|*sample_loss + |w2|*triple_loss )
// Weights folded in before the wave reduction (linear in per-dim terms).
// ---------------------------------------------------------------------------
__global__ __launch_bounds__(256) void score_copy_kernel(
    const float* __restrict__ w3,          // step_score_add_all (3)
    const float* __restrict__ sample_loss, // (E)
    const float* __restrict__ vj,          // node_rep_vj (E,D)
    const float* __restrict__ rel,         // rel_emb     (E,D)
    const float* __restrict__ qsrc,        // query_src_ts_emb (B,D)
    const float* __restrict__ qrel,        // query_rel_emb    (B,D)
    const int*   __restrict__ edges,       // selected_edges (E,9)
    const float* __restrict__ visited,     // visited_nodes_reg (E)
    float* __restrict__ visited_out,       // (E) passthrough
    float* __restrict__ score_out)         // (E)
{
    // Fused passthrough: first 256 blocks copy visited (EE floats = 65536 f4).
    if (blockIdx.x < 256) {
        const int t = blockIdx.x * 256 + threadIdx.x;
        ((f4*)visited_out)[t] = ((const f4*)visited)[t];
    }

    const int gwave = (blockIdx.x * blockDim.x + threadIdx.x) >> 6;
    const int lane  = threadIdx.x & 63;
    if (gwave >= EE) return;
    const int e = gwave;
    const int b = edges[(size_t)e * 9 + 8];   // qidx (uniform across the wave)

    const f4 r  = ((const f4*)(rel  + (size_t)e * DD))[lane];
    const f4 v  = ((const f4*)(vj   + (size_t)e * DD))[lane];
    const f4 qs = ((const f4*)(qsrc + (size_t)b * DD))[lane];
    const f4 qr = ((const f4*)(qrel + (size_t)b * DD))[lane];

    const float w0 = fabsf(w3[0]);
    const float w1 = fabsf(w3[1]);
    const float w2 = fabsf(w3[2]);

    // identical accumulation order to the verified kernel (absmax stability)
    float relp = fabsf(qr.x - r.x) + fabsf(qr.y - r.y) +
                 fabsf(qr.z - r.z) + fabsf(qr.w - r.w);
    float trip = fabsf(qs.x + r.x - v.x) + fabsf(qs.y + r.y - v.y) +
                 fabsf(qs.z + r.z - v.z) + fabsf(qs.w + r.w - v.w);

    float p = w0 * relp + w2 * trip;
    #pragma unroll
    for (int m = 1; m < 64; m <<= 1) p += __shfl_xor(p, m, 64);

    if (lane == 0) score_out[e] = -(p + w1 * sample_loss[e]);
}

// ---------------------------------------------------------------------------
// Kernel 2: per-row top-50, fully register-resident, barrier-free inner loops.
// One block (4 waves) per batch row. Wave w owns chunk [w*1024,(w+1)*1024):
// 16 values/lane in 4x f4 registers. Each wave runs 50 iterative argmax
// rounds wave-synchronously (no __syncthreads, no LDS in the loop), clearing
// the winner in-register. The true global top-50 is contained in the union
// of per-chunk top-50s (any global top-50 element has <50 row elements above
// it, hence <50 in its own chunk). Wave 0 then merges the 200 candidates
// with 50 more argmax rounds over registers.
// Tie-breaking matches jax.lax.top_k exactly: descending value, then
// smallest index (strict '>' over ascending-index scan + explicit index
// compare in every cross-lane reduce).
// ---------------------------------------------------------------------------
__global__ __launch_bounds__(256) void topk_kernel(
    const float* __restrict__ scores,   // (B, E_PER) = target_score
    const int*   __restrict__ edges,    // selected_edges (E,9)
    float* __restrict__ pruned_out,     // (B*K*9) floats
    float* __restrict__ orig_out)       // (B*K)   floats
{
    __shared__ float cand_v[4 * KK];
    __shared__ int   cand_i[4 * KK];
    __shared__ int   s_sel[KK];

    const int b    = blockIdx.x;
    const int tid  = threadIdx.x;
    const int lane = tid & 63;
    const int wid  = tid >> 6;

    // load this wave's 1024-score chunk into registers (coalesced dwordx4)
    const int cb = wid * 1024;                                   // chunk base
    const f4* src = (const f4*)(scores + (size_t)b * E_PER) + (cb >> 2) + lane;
    f4 c0 = src[0];
    f4 c1 = src[64];
    f4 c2 = src[128];
    f4 c3 = src[192];
    // element (q,c) of this lane has row-local index ibase + 256*q + c
    const int ibase = cb + 4 * lane;

    for (int k = 0; k < KK; ++k) {
        float bv = -INFINITY;
        int   bi = 0x7fffffff;
        // ascending-index scan, strict '>' => smallest index wins ties
        #define SCAN(vec, q) \
            if (vec.x > bv) { bv = vec.x; bi = ibase + 256*q + 0; } \
            if (vec.y > bv) { bv = vec.y; bi = ibase + 256*q + 1; } \
            if (vec.z > bv) { bv = vec.z; bi = ibase + 256*q + 2; } \
            if (vec.w > bv) { bv = vec.w; bi = ibase + 256*q + 3; }
        SCAN(c0, 0) SCAN(c1, 1) SCAN(c2, 2) SCAN(c3, 3)
        #undef SCAN

        #pragma unroll
        for (int m = 1; m < 64; m <<= 1) {
            float ov = __shfl_xor(bv, m, 64);
            int   oi = __shfl_xor(bi, m, 64);
            if (ov > bv || (ov == bv && oi < bi)) { bv = ov; bi = oi; }
        }

        // clear the winner in its owner lane's registers (indices unique;
        // rel_i == 256q+c has a solution only for the true owner lane)
        const int rel_i = bi - ibase;
        #define CLR(vec, q) \
            if (rel_i == 256*q + 0) vec.x = -INFINITY; \
            if (rel_i == 256*q + 1) vec.y = -INFINITY; \
            if (rel_i == 256*q + 2) vec.z = -INFINITY; \
            if (rel_i == 256*q + 3) vec.w = -INFINITY;
        CLR(c0, 0) CLR(c1, 1) CLR(c2, 2) CLR(c3, 3)
        #undef CLR

        if (lane == 0) { cand_v[wid * KK + k] = bv; cand_i[wid * KK + k] = bi; }
    }
    __syncthreads();

    // wave 0: merge the 4*50 = 200 candidates (register-resident, 4/lane)
    if (wid == 0) {
        float mv[4]; int mi[4];
        #pragma unroll
        for (int rr = 0; rr < 4; ++rr) {
            const int t = lane + 64 * rr;
            const bool ok = t < 4 * KK;
            mv[rr] = ok ? cand_v[t] : -INFINITY;
            mi[rr] = ok ? cand_i[t] : 0x7fffffff;
        }
        for (int k = 0; k < KK; ++k) {
            float bv = -INFINITY; int bi = 0x7fffffff;
            #pragma unroll
            for (int rr = 0; rr < 4; ++rr)   // candidate order != index order:
                if (mv[rr] > bv || (mv[rr] == bv && mi[rr] < bi)) { bv = mv[rr]; bi = mi[rr]; }
            #pragma unroll
            for (int m = 1; m < 64; m <<= 1) {
                float ov = __shfl_xor(bv, m, 64);
                int   oi = __shfl_xor(bi, m, 64);
                if (ov > bv || (ov == bv && oi < bi)) { bv = ov; bi = oi; }
            }
            #pragma unroll
            for (int rr = 0; rr < 4; ++rr)   // clear by unique index match
                if (mi[rr] == bi) mv[rr] = -INFINITY;
            if (lane == 0) s_sel[k] = bi;
        }
    }
    __syncthreads();

    // pruned_edges: (B*K, 9) gather, written as float values (indices < 2^24)
    for (int t = tid; t < KK * 9; t += 256) {
        const int k = t / 9, j = t % 9;
        const int orig = b * E_PER + s_sel[k];
        pruned_out[(size_t)(b * KK + k) * 9 + j] = (float)edges[(size_t)orig * 9 + j];
    }
    for (int t = tid; t < KK; t += 256)
        orig_out[b * KK + t] = (float)(b * E_PER + s_sel[t]);
}

extern "C" void kernel_launch(void* const* d_in, const int* in_sizes, int n_in,
                              void* d_out, int out_size, void* d_ws, size_t ws_size,
                              hipStream_t stream) {
    const float* w        = (const float*)d_in[0];  // step_score_add_all (3,1)
    const float* visited  = (const float*)d_in[1];  // visited_nodes_reg (E)
    // d_in[2] src_ts_emb_special_set  -- unused by reference
    const float* sample   = (const float*)d_in[3];  // sample_loss (E)
    // d_in[4] node_rep_vi             -- unused by reference
    const float* vj       = (const float*)d_in[5];  // node_rep_vj (E,D)
    const float* rel      = (const float*)d_in[6];  // rel_emb (E,D)
    const float* qsrc     = (const float*)d_in[7];  // query_src_ts_emb (B,D)
    const float* qrel     = (const float*)d_in[8];  // query_rel_emb (B,D)
    const int*   edges    = (const int*)d_in[9];    // selected_edges (E,9)
    // d_in[10] max_edges = 50 (compile-time KK)

    float* out        = (float*)d_out;
    float* score_out  = out;                         // (E)
    float* visited_out= out + EE;                    // (E)
    float* pruned_out = out + 2 * EE;                // (B*K*9)
    float* orig_out   = out + 2 * EE + BB * KK * 9;  // (B*K)

    // one wave per edge -> E waves -> E/4 blocks of 256 threads
    score_copy_kernel<<<EE / 4, 256, 0, stream>>>(w, sample, vj, rel, qsrc, qrel,
                                                  edges, visited, visited_out,
                                                  score_out);
    topk_kernel<<<BB, 256, 0, stream>>>(score_out, edges, pruned_out, orig_out);
}